// Round 1
// baseline (1854.623 us; speedup 1.0000x reference)
//
#include <hip/hip_runtime.h>
#include <hip/hip_bf16.h>

// LSTM: B=256, T=2048, D=64, U=64. fp32.
// One workgroup per batch element (256 WGs ~= 1 per CU).
// 256 threads: thread g owns gate column g of the 4U=256 pre-activations.
// Weight columns (Wx[:,g], Wh[:,g]) live in registers (128 VGPRs).
// Input vector [x_t ; h_{t-1}] broadcast via LDS.

#define LSTM_B 256
#define LSTM_T 2048
#define LSTM_D 64
#define LSTM_U 64
#define LSTM_G 256   // 4*U

__device__ __forceinline__ float fast_sigmoid(float z) {
    return 1.0f / (1.0f + __expf(-z));
}

__device__ __forceinline__ float fast_tanh(float z) {
    float az = fabsf(z);
    float e = __expf(-2.0f * az);          // in (0,1], no overflow
    float t = (1.0f - e) / (1.0f + e);
    return copysignf(t, z);
}

__global__ __launch_bounds__(256)
void lstm_seq_kernel(const float* __restrict__ x,
                     const float* __restrict__ Wx,
                     const float* __restrict__ Wh,
                     const float* __restrict__ bias,
                     float* __restrict__ out)
{
    const int batch = blockIdx.x;
    const int g = threadIdx.x;            // gate column 0..255

    // ---- load weight columns into registers (coalesced across threads) ----
    float wx[LSTM_D];
    float wh[LSTM_U];
#pragma unroll
    for (int d = 0; d < LSTM_D; ++d) wx[d] = Wx[d * LSTM_G + g];
#pragma unroll
    for (int u = 0; u < LSTM_U; ++u) wh[u] = Wh[u * LSTM_G + g];
    const float b = bias[g];

    __shared__ __align__(16) float sIn[2 * LSTM_U];  // [0:64) x_t, [64:128) h
    __shared__ float sAct[LSTM_G];

    // init h = 0 in LDS; c in registers of threads 0..63
    float c = 0.0f;
    if (g >= 64 && g < 128) sIn[g] = 0.0f;

    const float* xb = x + (size_t)batch * LSTM_T * LSTM_D;
    float* ob = out + (size_t)batch * LSTM_T * (2 * LSTM_U);

    // prefetch x for t=0
    float xpre = 0.0f;
    if (g < LSTM_D) xpre = xb[g];

    __syncthreads();

    for (int t = 0; t < LSTM_T; ++t) {
        // publish x_t (prefetched last iteration)
        if (g < LSTM_D) sIn[g] = xpre;
        __syncthreads();                                   // SYNC-A

        // issue prefetch of x_{t+1} early: full compute phase hides latency
        if (g < LSTM_D && (t + 1) < LSTM_T) xpre = xb[(size_t)(t + 1) * LSTM_D + g];

        // z_g = b_g + x_t . Wx[:,g] + h . Wh[:,g]
        float a0 = 0.f, a1 = 0.f, a2 = 0.f, a3 = 0.f;
#pragma unroll
        for (int k = 0; k < LSTM_D; k += 4) {
            float4 v = *(const float4*)&sIn[k];
            a0 = fmaf(v.x, wx[k + 0], a0);
            a1 = fmaf(v.y, wx[k + 1], a1);
            a2 = fmaf(v.z, wx[k + 2], a2);
            a3 = fmaf(v.w, wx[k + 3], a3);
        }
#pragma unroll
        for (int k = 0; k < LSTM_U; k += 4) {
            float4 v = *(const float4*)&sIn[LSTM_U + k];
            a0 = fmaf(v.x, wh[k + 0], a0);
            a1 = fmaf(v.y, wh[k + 1], a1);
            a2 = fmaf(v.z, wh[k + 2], a2);
            a3 = fmaf(v.w, wh[k + 3], a3);
        }
        float z = b + ((a0 + a1) + (a2 + a3));

        // activation: columns [128,192) are candidate g -> tanh, rest sigmoid
        float act;
        if (g >= 128 && g < 192) act = fast_tanh(z);
        else                     act = fast_sigmoid(z);
        sAct[g] = act;
        __syncthreads();                                   // SYNC-B

        // state update by threads 0..63 (u = g)
        if (g < LSTM_U) {
            float i_g = sAct[g];
            float f_g = sAct[g + 64];
            float c_g = sAct[g + 128];
            float o_g = sAct[g + 192];
            c = f_g * c + i_g * c_g;
            float h = o_g * fast_tanh(c);
            sIn[LSTM_U + g] = h;                           // h for next step
            // output: cells first, then hidden
            ob[(size_t)t * 128 + g]      = c;
            ob[(size_t)t * 128 + 64 + g] = h;
        }
        // next loop's SYNC-A orders sIn writes vs. reads
    }
}

extern "C" void kernel_launch(void* const* d_in, const int* in_sizes, int n_in,
                              void* d_out, int out_size, void* d_ws, size_t ws_size,
                              hipStream_t stream) {
    const float* x  = (const float*)d_in[0];
    const float* Wx = (const float*)d_in[1];
    const float* Wh = (const float*)d_in[2];
    const float* b  = (const float*)d_in[3];
    float* out = (float*)d_out;

    hipLaunchKernelGGL(lstm_seq_kernel, dim3(LSTM_B), dim3(LSTM_G), 0, stream,
                       x, Wx, Wh, b, out);
}